// Round 12
// baseline (5351.168 us; speedup 1.0000x reference)
//
#include <hip/hip_runtime.h>

#define SLEN  128
#define BATCH 64
#define EMB   512
#define HID   512
#define DDEC  1024
#define ATT   256
#define VOC   32000
#define TSTEPS 63
#define SLOT  1024   // ints per 4KB slot

typedef _Float16 f16x4 __attribute__((ext_vector_type(4)));
typedef _Float16 f16x8 __attribute__((ext_vector_type(8)));
typedef float    f32x4 __attribute__((ext_vector_type(4)));

union HQ  { unsigned long long q[2]; f16x8 v; };
union HP  { _Float16 h[2]; unsigned u; };
union HP4 { _Float16 h[4]; f16x4 v4; unsigned long long u; };
union HPs { _Float16 h; unsigned short u; };

__device__ __forceinline__ float sigmoidf_(float x) { return 1.0f / (1.0f + __expf(-x)); }
__device__ __forceinline__ float tanhf_(float x)    { return 1.0f - 2.0f / (__expf(2.0f * x) + 1.0f); }

__device__ __forceinline__ void st_u32(void* p, unsigned v) {
    __hip_atomic_store((unsigned*)p, v, __ATOMIC_RELAXED, __HIP_MEMORY_SCOPE_AGENT);
}
__device__ __forceinline__ void st_u64(void* p, unsigned long long v) {
    __hip_atomic_store((unsigned long long*)p, v, __ATOMIC_RELAXED, __HIP_MEMORY_SCOPE_AGENT);
}
__device__ __forceinline__ void st_u16(void* p, unsigned short v) {
    __hip_atomic_store((unsigned short*)p, v, __ATOMIC_RELAXED, __HIP_MEMORY_SCOPE_AGENT);
}
__device__ __forceinline__ unsigned long long ld_u64(const void* p) {
    return __hip_atomic_load((const unsigned long long*)p, __ATOMIC_RELAXED, __HIP_MEMORY_SCOPE_AGENT);
}
__device__ __forceinline__ void st_i32(int* p, int v) {
    __hip_atomic_store(p, v, __ATOMIC_RELAXED, __HIP_MEMORY_SCOPE_AGENT);
}
__device__ __forceinline__ int ld_i32(const int* p) {
    return __hip_atomic_load(p, __ATOMIC_RELAXED, __HIP_MEMORY_SCOPE_AGENT);
}

// ---- detector-free barrier: arrival = 1 relaxed store; wave-0 polls all flags.
__device__ __forceinline__ void bar_arrive(int* flags, int myid, int epoch) {
    __syncthreads();                       // drains this block's data stores (vmcnt 0)
    if (threadIdx.x == 0) st_i32(flags + myid * SLOT, epoch);
}
__device__ __forceinline__ void bar_wait(int* flags, int nf, int epoch) {
    if ((int)threadIdx.x < 64) {
        bool done = false;
        while (!done) {
            bool ok = true;
            for (int i = threadIdx.x; i < nf; i += 64)
                ok = ok && (ld_i32(flags + i * SLOT) >= epoch);
            done = __all(ok);
            if (!done) __builtin_amdgcn_s_sleep(1);
        }
    }
    __syncthreads();
}

// ================= init =================
__global__ __launch_bounds__(256) void init_convert(
    const int* __restrict__ src, const int* __restrict__ trg,
    const float* __restrict__ enc_emb, const float* __restrict__ dec_emb,
    const float* __restrict__ Wf_ih, const float* __restrict__ Wf_hh,
    const float* __restrict__ Wb_ih, const float* __restrict__ Wb_hh,
    const float* __restrict__ Wa, const float* __restrict__ Wd_ih, const float* __restrict__ Wd_hh,
    float* __restrict__ out0,
    _Float16* __restrict__ Wenc16, _Float16* __restrict__ Wd16, _Float16* __restrict__ Wa16,
    _Float16* __restrict__ emb_src16, _Float16* __restrict__ predA,
    float* __restrict__ c_enc, _Float16* __restrict__ h16_enc, int* __restrict__ bar_ws)
{
    long idx = (long)blockIdx.x * 256 + threadIdx.x;
    if (idx < 2048000L) { out0[idx] = 0.f; return; }
    idx -= 2048000L;
    if (idx < 4194304L) {   // Wenc16 [dir][2048][1024]
        int dir = (int)(idx >> 21);
        int rem = (int)(idx & ((1 << 21) - 1));
        int rr = rem >> 10, c = rem & 1023;
        int d = rr >> 2, qg = rr & 3;
        const float* Wih = dir ? Wb_ih : Wf_ih;
        const float* Whh = dir ? Wb_hh : Wf_hh;
        float v = (c < 512) ? Wih[(long)(qg * 512 + d) * 512 + c]
                            : Whh[(long)(qg * 512 + d) * 512 + (c - 512)];
        Wenc16[idx] = (_Float16)v; return;
    }
    idx -= 4194304L;
    if (idx < 10485760L) {  // Wd16 [4096][2560]
        int rr = (int)(idx / 2560), c = (int)(idx % 2560);
        int d = rr >> 2, qg = rr & 3;
        float v = (c < 1536) ? Wd_ih[(long)(qg * 1024 + d) * 1536 + c]
                             : Wd_hh[(long)(qg * 1024 + d) * 1024 + (c - 1536)];
        Wd16[idx] = (_Float16)v; return;
    }
    idx -= 10485760L;
    if (idx < 262144L) {    // Wa16 [256][1024]
        int rr = (int)(idx >> 10), c = (int)(idx & 1023);
        Wa16[idx] = (_Float16)Wa[(long)rr * 2048 + c]; return;
    }
    idx -= 262144L;
    if (idx < 4194304L) {   // emb_src16
        int sb = (int)(idx >> 9), e = (int)(idx & 511);
        int tok = src[sb];
        emb_src16[idx] = (_Float16)enc_emb[(long)tok * 512 + e]; return;
    }
    idx -= 4194304L;
    if (idx < 2064384L) {   // predA emb cols
        int rI = (int)(idx >> 9), e = (int)(idx & 511);
        int tok = trg[rI];
        predA[(long)(64 + rI) * 2560 + 2048 + e] = (_Float16)dec_emb[(long)tok * 512 + e]; return;
    }
    idx -= 2064384L;
    if (idx < 65536L) { c_enc[idx] = 0.f; return; }
    idx -= 65536L;
    if (idx < 65536L) { h16_enc[idx] = (_Float16)0.f; return; }
    idx -= 65536L;
    if (idx < 655360L) { bar_ws[idx] = 0; }   // 640 slots x 1024 ints
}

// ================= cooperative encoder: 4 groups (dir x batch-half) x 64 blocks x 256 thr =================
__global__ __launch_bounds__(256, 1) void enc_coop(
    const _Float16* __restrict__ Wenc16, const _Float16* __restrict__ emb_src16,
    _Float16* __restrict__ h16_enc, float* __restrict__ c_enc,
    const float* __restrict__ bf, const float* __restrict__ bb,
    _Float16* __restrict__ enc_out16, int* __restrict__ bar_ws)
{
    __shared__ _Float16 Wl[32768];       // 64KB [kc32][gt2][512]
    __shared__ float gbuf[32][34];

    const int t = threadIdx.x, lane = t & 63, wv = t >> 6;
    const int blk = blockIdx.x;
    const int g = blk >> 6, wb = blk & 63;
    const int dir = g >> 1, bh = g & 1;
    const int r16 = lane & 15, kg = lane >> 4;
    int* eflags = bar_ws + (384 + g * 64) * SLOT;

    #pragma unroll
    for (int i = 0; i < 16; ++i) {
        int h0 = (i * 256 + t) * 8;
        int kc = h0 >> 10;
        int rem = h0 & 1023;
        int gt2 = rem >> 9, l = (rem >> 3) & 63;
        f16x8 v = *(const f16x8*)(Wenc16 +
            ((size_t)(dir * 2048 + wb * 32 + gt2 * 16 + (l & 15))) * 1024 + (l >> 4) * 8 + kc * 32);
        *(f16x8*)&Wl[h0] = v;
    }

    const float* bias = dir ? bb : bf;
    const int pb = t & 31, dp = t >> 5;
    const int dl0 = dp * 2;
    float bias2[2][4], creg2[2] = {0.f, 0.f};
    if (t < 128) {
        #pragma unroll
        for (int j = 0; j < 2; ++j)
            #pragma unroll
            for (int q = 0; q < 4; ++q)
                bias2[j][q] = bias[q * 512 + wb * 8 + dl0 + j];
    }
    __syncthreads();

    for (int s = 0; s < SLEN; ++s) {
        const int par = s & 1;
        const int s_eff = dir ? (127 - s) : s;
        const int gt = wv & 1, mb = wv >> 1;
        const int arow = bh * 32 + mb * 16 + r16;
        const _Float16* Ax = emb_src16 + ((size_t)(s_eff * 64 + arow)) * 512 + kg * 8;
        const unsigned long long* Hq =
            (const unsigned long long*)(h16_enc + ((size_t)((par * 2 + dir) * 64 + arow)) * 512);
        f32x4 acc = {};
        {
            f16x8 aX[16];
            #pragma unroll
            for (int kc = 0; kc < 16; ++kc) aX[kc] = *(const f16x8*)(Ax + kc * 32);
            #pragma unroll
            for (int kc = 0; kc < 16; ++kc) {
                f16x8 bw = *(const f16x8*)&Wl[kc * 1024 + gt * 512 + lane * 8];
                acc = __builtin_amdgcn_mfma_f32_16x16x32_f16(aX[kc], bw, acc, 0, 0, 0);
            }
            HQ hq[16];
            #pragma unroll
            for (int kc = 0; kc < 16; ++kc) {
                hq[kc].q[0] = ld_u64(Hq + kc * 8 + kg * 2);
                hq[kc].q[1] = ld_u64(Hq + kc * 8 + kg * 2 + 1);
            }
            #pragma unroll
            for (int kc = 0; kc < 16; ++kc) {
                f16x8 bw = *(const f16x8*)&Wl[(16 + kc) * 1024 + gt * 512 + lane * 8];
                acc = __builtin_amdgcn_mfma_f32_16x16x32_f16(hq[kc].v, bw, acc, 0, 0, 0);
            }
        }
        #pragma unroll
        for (int rI = 0; rI < 4; ++rI)
            gbuf[gt * 16 + (lane & 15)][mb * 16 + kg * 4 + rI] = acc[rI];
        __syncthreads();
        if (t < 128) {
            HP hp;
            #pragma unroll
            for (int j = 0; j < 2; ++j) {
                const int dl = dl0 + j;
                float g0 = gbuf[dl * 4 + 0][pb] + bias2[j][0];
                float g1 = gbuf[dl * 4 + 1][pb] + bias2[j][1];
                float g2 = gbuf[dl * 4 + 2][pb] + bias2[j][2];
                float g3 = gbuf[dl * 4 + 3][pb] + bias2[j][3];
                float c2 = sigmoidf_(g1) * creg2[j] + sigmoidf_(g0) * tanhf_(g2);
                float h2 = sigmoidf_(g3) * tanhf_(c2);
                creg2[j] = c2;
                hp.h[j] = (_Float16)h2;
            }
            const int bglob = bh * 32 + pb;
            const int d0 = wb * 8 + dl0;
            st_u32((void*)(h16_enc + ((size_t)((par ^ 1) * 2 + dir) * 64 + bglob) * 512 + d0), hp.u);
            *(unsigned*)(enc_out16 + ((size_t)s_eff * 64 + bglob) * 1024 + dir * 512 + d0) = hp.u;
        }
        bar_arrive(eflags, wb, s + 1);
        bar_wait(eflags, 64, s + 1);
    }
    if (t < 128) {
        const int bglob = bh * 32 + pb;
        const int d0 = wb * 8 + dl0;
        c_enc[((size_t)dir * 64 + bglob) * 512 + d0] = creg2[0];
        c_enc[((size_t)dir * 64 + bglob) * 512 + d0 + 1] = creg2[1];
    }
}

// ================= cooperative decoder: 256 blocks x 256 thr =================
// 64 attn blocks (batch=blk, plus a 1-d gate sliver) + 192 gate blocks (5 d each, Wd in LDS).
// Gate blocks overlap emb+h K-segments with attention; only ctx segment waits on cf.
__global__ __launch_bounds__(256, 1) void dec_coop(
    const _Float16* __restrict__ Wd16, const _Float16* __restrict__ Wa16,
    const float* __restrict__ bd, const float* __restrict__ vvec,
    const int* __restrict__ src, const _Float16* __restrict__ enc_part16,
    const _Float16* __restrict__ enc_out16, const float* __restrict__ c_enc,
    _Float16* __restrict__ predA, int* __restrict__ bar_ws)
{
    __shared__ char smem[110592];
    _Float16* Wl = (_Float16*)smem;                      // gate: 100KB (nr=20); attn: 10KB (nr=4)
    float (*gbuf)[66] = (float(*)[66])(smem + 102400);   // 20 x 66 x 4B
    float* ha   = (float*)(smem + 20480);                // attn-only buffers (after attn Wl end)
    float* sv   = (float*)(smem + 21504);
    float* sc   = (float*)(smem + 22528);
    float* red  = (float*)(smem + 23040);
    float* ectx = (float*)(smem + 24576);                // 2*128*8 floats = 8KB (also energy partials)

    const int t = threadIdx.x, lane = t & 63, wv = t >> 6;
    const int r16 = lane & 15, kg = lane >> 4;
    const int blk = blockIdx.x;
    const bool isAttn = blk < 64;
    const int nd = isAttn ? 1 : 5;
    const int nr = nd * 4;
    const int dbase = isAttn ? blk : (64 + (blk - 64) * 5);
    const int rowbase = dbase * 4;
    int* cf  = bar_ws;                   // 64 ctx flags
    int* hs  = bar_ws + 64 * SLOT;       // 256 h flags
    int* hf0 = bar_ws + 320 * SLOT;      // 64 h0 flags

    // stage Wd rows [rowbase, rowbase+nr) into LDS, chunk-linear [kc][row][32]
    {
        const int nfrag = nr * 320;
        for (int f = t; f < nfrag; f += 256) {
            int kc = f / (nr * 4);
            int rem = f - kc * (nr * 4);
            int r = rem >> 2, kq = rem & 3;
            *(f16x8*)&Wl[((kc * nr + r) << 5) + kq * 8] =
                *(const f16x8*)(Wd16 + (size_t)(rowbase + r) * 2560 + kc * 32 + kq * 8);
        }
    }

    // pointwise pairs (each thread up to 2 of nd*64 (d_local,b) pairs)
    float creg[2] = {0.f, 0.f};
    float biasA[2][4];
    int pdk[2] = {0, 0}, pbk[2] = {0, 0};
    bool pvalid[2] = {false, false};
    #pragma unroll
    for (int k = 0; k < 2; ++k) {
        int p = t + k * 256;
        if (p < nd * 64) {
            pvalid[k] = true;
            pdk[k] = p >> 6; pbk[k] = p & 63;
            int dg = dbase + pdk[k];
            #pragma unroll
            for (int q = 0; q < 4; ++q) biasA[k][q] = bd[q * 1024 + dg];
            creg[k] = (dg < 512) ? c_enc[(size_t)pbk[k] * 512 + dg]
                                 : c_enc[(size_t)(64 + pbk[k]) * 512 + (dg - 512)];
        }
    }

    const int rc0 = (r16 < nr) ? r16 : (nr - 1);
    const int rc1 = (16 + r16 < nr) ? (16 + r16) : (nr - 1);

    if (isAttn) {
        sv[t] = vvec[t];
        const int d0 = t * 4;
        const size_t rbase = (d0 < 512) ? (size_t)(127 * 64 + blk) * 1024
                                        : (size_t)(0 * 64 + blk) * 1024;
        HP4 o;
        o.h[0] = enc_out16[rbase + d0];
        o.h[1] = enc_out16[rbase + d0 + 1];
        o.h[2] = enc_out16[rbase + d0 + 2];
        o.h[3] = enc_out16[rbase + d0 + 3];
        st_u64((void*)(predA + (size_t)blk * 2560 + d0), o.u);
        bar_arrive(hf0, blk, 1);
    } else {
        __syncthreads();
    }

    for (int tt = 0; tt < TSTEPS; ++tt) {
        if (tt == 0) bar_wait(hf0, 64, 1); else bar_wait(hs, 256, tt);

        if (isAttn) {
            const int wb = blk;
            // P1: hatt via 16-batch-group MFMA (A prefetched to regs)
            {
                const int base_m = wb & 48;
                const _Float16* Ahh = predA + ((size_t)(tt * 64 + base_m + r16)) * 2560 + kg * 8;
                f16x8 aP[32];
                #pragma unroll
                for (int kc = 0; kc < 32; ++kc) aP[kc] = *(const f16x8*)(Ahh + kc * 32);
                f32x4 acc4[4] = {};
                #pragma unroll
                for (int kc = 0; kc < 32; ++kc) {
                    #pragma unroll
                    for (int jj = 0; jj < 4; ++jj) {
                        f16x8 bw = *(const f16x8*)(Wa16 +
                            ((size_t)((wv * 4 + jj) * 16 + r16)) * 1024 + kg * 8 + kc * 32);
                        acc4[jj] = __builtin_amdgcn_mfma_f32_16x16x32_f16(aP[kc], bw, acc4[jj], 0, 0, 0);
                    }
                }
                if (kg == ((wb & 15) >> 2)) {
                    #pragma unroll
                    for (int jj = 0; jj < 4; ++jj)
                        ha[(wv * 4 + jj) * 16 + r16] = acc4[jj][wb & 3];
                }
            }
            __syncthreads();
            // P2: energy (256 threads: s = t&127, j-half = t>>7)
            {
                const int s = t & 127, jh = t >> 7;
                const f16x8* ep = (const f16x8*)(enc_part16 + ((size_t)s * 64 + wb) * 256 + jh * 128);
                float acc = 0.f;
                #pragma unroll
                for (int j8 = 0; j8 < 16; ++j8) {
                    f16x8 e = ep[j8];
                    #pragma unroll
                    for (int u = 0; u < 8; ++u)
                        acc += tanhf_(ha[jh * 128 + j8 * 8 + u] + (float)e[u]) * sv[jh * 128 + j8 * 8 + u];
                }
                ectx[t] = acc;
            }
            __syncthreads();
            if (t < 128) {
                float scv = ectx[t] + ectx[128 + t];
                scv = (src[t * 64 + wb] != 0) ? scv : -1e10f;
                sc[t] = scv;
                float v = scv;
                #pragma unroll
                for (int off = 32; off > 0; off >>= 1) v = fmaxf(v, __shfl_xor(v, off));
                if (lane == 0) red[t >> 6] = v;
            }
            __syncthreads();
            {
                const float mx = fmaxf(red[0], red[1]);
                if (t < 128) {
                    float e = __expf(sc[t] - mx);
                    sc[t] = e;
                    float v = e;
                    #pragma unroll
                    for (int off = 32; off > 0; off >>= 1) v += __shfl_xor(v, off);
                    if (lane == 0) red[2 + (t >> 6)] = v;
                }
            }
            __syncthreads();
            // ctx: s-split x2, 8 dims per thread
            {
                const float inv = 1.0f / (red[2] + red[3]);
                const int eg = t & 127, sh = t >> 7;
                float a[8] = {0.f, 0.f, 0.f, 0.f, 0.f, 0.f, 0.f, 0.f};
                #pragma unroll 8
                for (int i = 0; i < 64; ++i) {
                    const int sI = sh * 64 + i;
                    const float as = sc[sI] * inv;
                    f16x8 ev = *(const f16x8*)(enc_out16 + ((size_t)sI * 64 + wb) * 1024 + eg * 8);
                    #pragma unroll
                    for (int u = 0; u < 8; ++u) a[u] += as * (float)ev[u];
                }
                #pragma unroll
                for (int u = 0; u < 8; ++u) ectx[t * 8 + u] = a[u];
            }
            __syncthreads();
            if (t < 128) {
                HP4 o1, o2;
                #pragma unroll
                for (int u = 0; u < 4; ++u) {
                    o1.h[u] = (_Float16)(ectx[t * 8 + u] + ectx[(128 + t) * 8 + u]);
                    o2.h[u] = (_Float16)(ectx[t * 8 + 4 + u] + ectx[(128 + t) * 8 + 4 + u]);
                }
                st_u64((void*)(predA + ((size_t)(64 + tt * 64 + wb)) * 2560 + 1024 + t * 8), o1.u);
                st_u64((void*)(predA + ((size_t)(64 + tt * 64 + wb)) * 2560 + 1024 + t * 8 + 4), o2.u);
            }
            bar_arrive(cf, wb, tt + 1);
        }

        // ---- gates: nr rows x 64 batch; B from LDS; A prefetched to regs (16-deep windows)
        {
            const int mb = wv;
            const _Float16* Ae = predA + ((size_t)(64 + tt * 64 + mb * 16 + r16)) * 2560 + kg * 8;
            const _Float16* Ahp = predA + ((size_t)(tt * 64 + mb * 16 + r16)) * 2560 + kg * 8;
            f32x4 acc0 = {}, acc1 = {};
            f16x8 aR[16];
            // emb: W chunks 0..15, A cols 2048+
            #pragma unroll
            for (int kc = 0; kc < 16; ++kc) aR[kc] = *(const f16x8*)(Ae + 2048 + kc * 32);
            #pragma unroll
            for (int kc = 0; kc < 16; ++kc) {
                acc0 = __builtin_amdgcn_mfma_f32_16x16x32_f16(aR[kc], *(const f16x8*)&Wl[((kc * nr + rc0) << 5) + kg * 8], acc0, 0, 0, 0);
                if (!isAttn)
                    acc1 = __builtin_amdgcn_mfma_f32_16x16x32_f16(aR[kc], *(const f16x8*)&Wl[((kc * nr + rc1) << 5) + kg * 8], acc1, 0, 0, 0);
            }
            // h lo: W chunks 48..63, A cols 0+
            #pragma unroll
            for (int kc = 0; kc < 16; ++kc) aR[kc] = *(const f16x8*)(Ahp + kc * 32);
            #pragma unroll
            for (int kc = 0; kc < 16; ++kc) {
                acc0 = __builtin_amdgcn_mfma_f32_16x16x32_f16(aR[kc], *(const f16x8*)&Wl[(((48 + kc) * nr + rc0) << 5) + kg * 8], acc0, 0, 0, 0);
                if (!isAttn)
                    acc1 = __builtin_amdgcn_mfma_f32_16x16x32_f16(aR[kc], *(const f16x8*)&Wl[(((48 + kc) * nr + rc1) << 5) + kg * 8], acc1, 0, 0, 0);
            }
            // h hi: W chunks 64..79, A cols 512+
            #pragma unroll
            for (int kc = 0; kc < 16; ++kc) aR[kc] = *(const f16x8*)(Ahp + 512 + kc * 32);
            #pragma unroll
            for (int kc = 0; kc < 16; ++kc) {
                acc0 = __builtin_amdgcn_mfma_f32_16x16x32_f16(aR[kc], *(const f16x8*)&Wl[(((64 + kc) * nr + rc0) << 5) + kg * 8], acc0, 0, 0, 0);
                if (!isAttn)
                    acc1 = __builtin_amdgcn_mfma_f32_16x16x32_f16(aR[kc], *(const f16x8*)&Wl[(((64 + kc) * nr + rc1) << 5) + kg * 8], acc1, 0, 0, 0);
            }
            bar_wait(cf, 64, tt + 1);
            // ctx lo: W chunks 16..31, A cols 1024+
            #pragma unroll
            for (int kc = 0; kc < 16; ++kc) aR[kc] = *(const f16x8*)(Ae + 1024 + kc * 32);
            #pragma unroll
            for (int kc = 0; kc < 16; ++kc) {
                acc0 = __builtin_amdgcn_mfma_f32_16x16x32_f16(aR[kc], *(const f16x8*)&Wl[(((16 + kc) * nr + rc0) << 5) + kg * 8], acc0, 0, 0, 0);
                if (!isAttn)
                    acc1 = __builtin_amdgcn_mfma_f32_16x16x32_f16(aR[kc], *(const f16x8*)&Wl[(((16 + kc) * nr + rc1) << 5) + kg * 8], acc1, 0, 0, 0);
            }
            // ctx hi: W chunks 32..47, A cols 1536+
            #pragma unroll
            for (int kc = 0; kc < 16; ++kc) aR[kc] = *(const f16x8*)(Ae + 1536 + kc * 32);
            #pragma unroll
            for (int kc = 0; kc < 16; ++kc) {
                acc0 = __builtin_amdgcn_mfma_f32_16x16x32_f16(aR[kc], *(const f16x8*)&Wl[(((32 + kc) * nr + rc0) << 5) + kg * 8], acc0, 0, 0, 0);
                if (!isAttn)
                    acc1 = __builtin_amdgcn_mfma_f32_16x16x32_f16(aR[kc], *(const f16x8*)&Wl[(((32 + kc) * nr + rc1) << 5) + kg * 8], acc1, 0, 0, 0);
            }
            // C/D: col = lane&15 -> gate row (N), row = kg*4+rI -> batch (M)
            const int nc0 = lane & 15;
            if (nc0 < nr) {
                #pragma unroll
                for (int rI = 0; rI < 4; ++rI)
                    gbuf[nc0][mb * 16 + kg * 4 + rI] = acc0[rI];
            }
            const int nc1 = 16 + (lane & 15);
            if (!isAttn && nc1 < nr) {
                #pragma unroll
                for (int rI = 0; rI < 4; ++rI)
                    gbuf[nc1][mb * 16 + kg * 4 + rI] = acc1[rI];
            }
        }
        __syncthreads();
        // pointwise: up to 2 pairs per thread, 2B h store
        #pragma unroll
        for (int k = 0; k < 2; ++k) {
            if (pvalid[k]) {
                float g0 = gbuf[pdk[k] * 4 + 0][pbk[k]] + biasA[k][0];
                float g1 = gbuf[pdk[k] * 4 + 1][pbk[k]] + biasA[k][1];
                float g2 = gbuf[pdk[k] * 4 + 2][pbk[k]] + biasA[k][2];
                float g3 = gbuf[pdk[k] * 4 + 3][pbk[k]] + biasA[k][3];
                float c2 = sigmoidf_(g1) * creg[k] + sigmoidf_(g0) * tanhf_(g2);
                float h2 = sigmoidf_(g3) * tanhf_(c2);
                creg[k] = c2;
                HPs hp; hp.h = (_Float16)h2;
                st_u16((void*)(predA + ((size_t)(64 + tt * 64 + pbk[k])) * 2560 + dbase + pdk[k]), hp.u);
            }
        }
        bar_arrive(hs, blk, tt + 1);
    }
}

// ================= fallback per-step kernels (validated) =================
__global__ __launch_bounds__(64) void enc_step_mfma(
    const _Float16* __restrict__ Wenc16, const _Float16* __restrict__ emb_src16,
    _Float16* __restrict__ h16_enc, float* __restrict__ c_enc,
    const float* __restrict__ bf, const float* __restrict__ bb,
    _Float16* __restrict__ enc_out16, int s)
{
    __shared__ float gbuf[16 * 66];
    const int lane = threadIdx.x;
    const int blk = blockIdx.x;
    const int dir = blk >> 7, tile = blk & 127;
    const int par = s & 1;
    const int s_eff = dir ? (SLEN - 1 - s) : s;
    const int r16 = lane & 15, kg = lane >> 4;

    const _Float16* Bw = Wenc16 + ((size_t)(dir * 2048 + tile * 16 + r16)) * 1024 + kg * 8;
    const _Float16* Ax = emb_src16 + ((size_t)(s_eff * 64 + r16)) * 512 + kg * 8;
    const _Float16* Ah = h16_enc + ((size_t)((par * 2 + dir) * 64 + r16)) * 512 + kg * 8;

    f32x4 acc[4] = {};
    #pragma unroll 4
    for (int kc = 0; kc < 16; ++kc) {
        f16x8 bfr = *(const f16x8*)(Bw + kc * 32);
        #pragma unroll
        for (int m = 0; m < 4; ++m) {
            f16x8 a = *(const f16x8*)(Ax + kc * 32 + (size_t)m * 16 * 512);
            acc[m] = __builtin_amdgcn_mfma_f32_16x16x32_f16(a, bfr, acc[m], 0, 0, 0);
        }
    }
    #pragma unroll 4
    for (int kc = 0; kc < 16; ++kc) {
        f16x8 bfr = *(const f16x8*)(Bw + 512 + kc * 32);
        #pragma unroll
        for (int m = 0; m < 4; ++m) {
            f16x8 a = *(const f16x8*)(Ah + kc * 32 + (size_t)m * 16 * 512);
            acc[m] = __builtin_amdgcn_mfma_f32_16x16x32_f16(a, bfr, acc[m], 0, 0, 0);
        }
    }
    #pragma unroll
    for (int m = 0; m < 4; ++m)
        #pragma unroll
        for (int rI = 0; rI < 4; ++rI)
            gbuf[r16 * 66 + m * 16 + kg * 4 + rI] = acc[m][rI];
    __syncthreads();

    const float* bias = dir ? bb : bf;
    const int b = lane;
    #pragma unroll
    for (int dl = 0; dl < 4; ++dl) {
        const int d = tile * 4 + dl;
        float g0 = gbuf[(dl * 4 + 0) * 66 + b] + bias[d];
        float g1 = gbuf[(dl * 4 + 1) * 66 + b] + bias[512 + d];
        float g2 = gbuf[(dl * 4 + 2) * 66 + b] + bias[1024 + d];
        float g3 = gbuf[(dl * 4 + 3) * 66 + b] + bias[1536 + d];
        const size_t cur = ((size_t)(par * 2 + dir) * 64 + b) * 512 + d;
        const size_t nxt = ((size_t)((par ^ 1) * 2 + dir) * 64 + b) * 512 + d;
        float c2 = sigmoidf_(g1) * c_enc[cur] + sigmoidf_(g0) * tanhf_(g2);
        float h2 = sigmoidf_(g3) * tanhf_(c2);
        c_enc[nxt] = c2;
        h16_enc[nxt] = (_Float16)h2;
        enc_out16[((size_t)s_eff * 64 + b) * 1024 + dir * 512 + d] = (_Float16)h2;
    }
}

__global__ __launch_bounds__(256) void dec_init(
    const _Float16* __restrict__ enc_out16, const float* __restrict__ c_enc,
    _Float16* __restrict__ predA, float* __restrict__ c_dec)
{
    int idx = blockIdx.x * 256 + threadIdx.x;
    int b = (idx >> 10) & 63, d = idx & 1023;
    if (idx < 65536) {
        _Float16 v = (d < 512) ? enc_out16[(size_t)(127 * 64 + b) * 1024 + d]
                               : enc_out16[(size_t)(0 * 64 + b) * 1024 + d];
        predA[(size_t)b * 2560 + d] = v;
    } else {
        float v = (d < 512) ? c_enc[((size_t)(0 * 2 + 0) * 64 + b) * 512 + d]
                            : c_enc[((size_t)(0 * 2 + 1) * 64 + b) * 512 + (d - 512)];
        c_dec[(size_t)b * 1024 + d] = v;
    }
}

__global__ __launch_bounds__(64) void hatt_mfma(
    const _Float16* __restrict__ predA, const _Float16* __restrict__ Wa16,
    float* __restrict__ hatt, int t)
{
    const int lane = threadIdx.x;
    const int tile = blockIdx.x;
    const int r16 = lane & 15, kg = lane >> 4;
    const _Float16* Ap = predA + ((size_t)(t * 64 + r16)) * 2560 + kg * 8;
    const _Float16* Bw = Wa16 + ((size_t)(tile * 16 + r16)) * 1024 + kg * 8;
    f32x4 acc[4] = {};
    #pragma unroll 4
    for (int kc = 0; kc < 32; ++kc) {
        f16x8 bfr = *(const f16x8*)(Bw + kc * 32);
        #pragma unroll
        for (int m = 0; m < 4; ++m) {
            f16x8 a = *(const f16x8*)(Ap + kc * 32 + (size_t)m * 16 * 2560);
            acc[m] = __builtin_amdgcn_mfma_f32_16x16x32_f16(a, bfr, acc[m], 0, 0, 0);
        }
    }
    #pragma unroll
    for (int m = 0; m < 4; ++m)
        #pragma unroll
        for (int rI = 0; rI < 4; ++rI)
            hatt[(size_t)(m * 16 + kg * 4 + rI) * 256 + tile * 16 + r16] = acc[m][rI];
}

__global__ __launch_bounds__(256) void attn_step(
    const int* __restrict__ src, const float* __restrict__ hatt, const float* __restrict__ vvec,
    const _Float16* __restrict__ enc_part16, const _Float16* __restrict__ enc_out16,
    _Float16* __restrict__ predA, int t)
{
    __shared__ float ha[256], sv[256], sc[128], red[128];
    const int b = blockIdx.x, tid = threadIdx.x;
    ha[tid] = hatt[b * 256 + tid];
    sv[tid] = vvec[tid];
    __syncthreads();
    if (tid < 128) {
        const f16x8* ep = (const f16x8*)(enc_part16 + ((size_t)tid * 64 + b) * 256);
        float acc = 0.f;
        #pragma unroll 4
        for (int j8 = 0; j8 < 32; ++j8) {
            f16x8 e = ep[j8];
            #pragma unroll
            for (int u = 0; u < 8; ++u)
                acc += tanhf_(ha[j8 * 8 + u] + (float)e[u]) * sv[j8 * 8 + u];
        }
        float scv = (src[tid * 64 + b] != 0) ? acc : -1e10f;
        sc[tid] = scv; red[tid] = scv;
    }
    __syncthreads();
    for (int off = 64; off > 0; off >>= 1) { if (tid < off) red[tid] = fmaxf(red[tid], red[tid + off]); __syncthreads(); }
    const float mx = red[0];
    __syncthreads();
    if (tid < 128) { float e = __expf(sc[tid] - mx); sc[tid] = e; red[tid] = e; }
    __syncthreads();
    for (int off = 64; off > 0; off >>= 1) { if (tid < off) red[tid] += red[tid + off]; __syncthreads(); }
    const float inv = 1.0f / red[0];
    __syncthreads();

    float a0 = 0.f, a1 = 0.f, a2 = 0.f, a3 = 0.f;
    for (int sI = 0; sI < 128; ++sI) {
        float as = sc[sI] * inv;
        f16x4 ev = *(const f16x4*)(enc_out16 + ((size_t)sI * 64 + b) * 1024 + tid * 4);
        a0 += as * (float)ev[0]; a1 += as * (float)ev[1];
        a2 += as * (float)ev[2]; a3 += as * (float)ev[3];
    }
    f16x4 o = { (_Float16)a0, (_Float16)a1, (_Float16)a2, (_Float16)a3 };
    *(f16x4*)(predA + ((size_t)(64 + t * 64 + b)) * 2560 + 1024 + tid * 4) = o;
}

__global__ __launch_bounds__(64) void dec_gates(
    const _Float16* __restrict__ Wd16, const float* __restrict__ bd,
    float* __restrict__ c_dec, _Float16* __restrict__ predA, int t)
{
    __shared__ float gbuf[16 * 66];
    const int lane = threadIdx.x;
    const int tile = blockIdx.x;
    const int par = t & 1;
    const int r16 = lane & 15, kg = lane >> 4;
    const _Float16* Bw = Wd16 + ((size_t)(tile * 16 + r16)) * 2560 + kg * 8;
    const _Float16* At = predA + ((size_t)(64 + t * 64 + r16)) * 2560 + kg * 8;
    const _Float16* Ah = predA + ((size_t)(t * 64 + r16)) * 2560 + kg * 8;
    f32x4 acc[4] = {};
    #pragma unroll 4
    for (int kc = 0; kc < 16; ++kc) {
        f16x8 bfr = *(const f16x8*)(Bw + kc * 32);
        #pragma unroll
        for (int m = 0; m < 4; ++m) {
            f16x8 a = *(const f16x8*)(At + 2048 + kc * 32 + (size_t)m * 16 * 2560);
            acc[m] = __builtin_amdgcn_mfma_f32_16x16x32_f16(a, bfr, acc[m], 0, 0, 0);
        }
    }
    #pragma unroll 4
    for (int kc = 0; kc < 32; ++kc) {
        f16x8 bfr = *(const f16x8*)(Bw + 512 + kc * 32);
        #pragma unroll
        for (int m = 0; m < 4; ++m) {
            f16x8 a = *(const f16x8*)(At + 1024 + kc * 32 + (size_t)m * 16 * 2560);
            acc[m] = __builtin_amdgcn_mfma_f32_16x16x32_f16(a, bfr, acc[m], 0, 0, 0);
        }
    }
    #pragma unroll 4
    for (int kc = 0; kc < 32; ++kc) {
        f16x8 bfr = *(const f16x8*)(Bw + 1536 + kc * 32);
        #pragma unroll
        for (int m = 0; m < 4; ++m) {
            f16x8 a = *(const f16x8*)(Ah + kc * 32 + (size_t)m * 16 * 2560);
            acc[m] = __builtin_amdgcn_mfma_f32_16x16x32_f16(a, bfr, acc[m], 0, 0, 0);
        }
    }
    #pragma unroll
    for (int m = 0; m < 4; ++m)
        #pragma unroll
        for (int rI = 0; rI < 4; ++rI)
            gbuf[r16 * 66 + m * 16 + kg * 4 + rI] = acc[m][rI];
    __syncthreads();

    const int b = lane;
    #pragma unroll
    for (int dl = 0; dl < 4; ++dl) {
        const int d = tile * 4 + dl;
        float g0 = gbuf[(dl * 4 + 0) * 66 + b] + bd[d];
        float g1 = gbuf[(dl * 4 + 1) * 66 + b] + bd[1024 + d];
        float g2 = gbuf[(dl * 4 + 2) * 66 + b] + bd[2048 + d];
        float g3 = gbuf[(dl * 4 + 3) * 66 + b] + bd[3072 + d];
        float c2 = sigmoidf_(g1) * c_dec[(size_t)(par * 64 + b) * 1024 + d] + sigmoidf_(g0) * tanhf_(g2);
        float h2 = sigmoidf_(g3) * tanhf_(c2);
        c_dec[(size_t)((par ^ 1) * 64 + b) * 1024 + d] = c2;
        predA[((size_t)(64 + t * 64 + b)) * 2560 + d] = (_Float16)h2;
    }
}

// ================= generic fp16-A MFMA GEMM =================
__global__ __launch_bounds__(256, 2) void gemm_a16(
    const _Float16* __restrict__ A, int lda,
    const float* __restrict__ B, int ldb,
    const float* __restrict__ bias,
    void* __restrict__ Cv, int ldc, int K, int Mvalid, int ntn, int c16)
{
    __shared__ _Float16 As[8192];
    __shared__ _Float16 Bs[8192];

    const int nwg = gridDim.x;
    const int id = blockIdx.x;
    const int q = nwg >> 3, r = nwg & 7;
    const int xcd = id & 7, ix = id >> 3;
    const int wg = (xcd < r) ? (xcd * (q + 1) + ix) : (r * (q + 1) + (xcd - r) * q + ix);
    const int per = ntn << 3;
    const int g = wg / per, rem = wg % per;
    const int mt = g * 8 + (rem & 7), nt = rem >> 3;

    const int t = threadIdx.x, lane = t & 63, wid = t >> 6;
    const int wr = wid >> 1, wc = wid & 1;

    const int arow_s = t >> 3, ac8 = t & 7;
    const int brow_s = t >> 4, bc4 = t & 15;
    const _Float16* Ap = A + (size_t)(mt * 128 + arow_s) * lda + ac8 * 8;
    const float*    Bp = B + (size_t)(nt * 128 + brow_s) * ldb + bc4 * 4;
    const int awx = (ac8 * 8) ^ ((arow_s & 7) << 3);
    const int bwx = (bc4 * 4) ^ ((brow_s & 7) << 3);

    const int kts = K >> 6;
    f32x4 acc[4][4] = {};
    f16x8 ra[4]; float4 rb[8];
    #pragma unroll
    for (int i = 0; i < 4; ++i) ra[i] = *(const f16x8*)(Ap + (size_t)i * 32 * lda);
    #pragma unroll
    for (int i = 0; i < 8; ++i) rb[i] = *(const float4*)(Bp + (size_t)i * 16 * ldb);

    const int abase = (wr * 64 + (lane & 15)) * 64 + (lane >> 4) * 8;
    const int bbase = (wc * 64 + (lane & 15)) * 64 + (lane >> 4) * 8;
    const int sxor = (lane & 7) << 3;

    for (int kt = 0; kt < kts; ++kt) {
        f16x4 cb[8];
        #pragma unroll
        for (int i = 0; i < 8; ++i)
            cb[i] = (f16x4){(_Float16)rb[i].x, (_Float16)rb[i].y, (_Float16)rb[i].z, (_Float16)rb[i].w};
        __syncthreads();
        #pragma unroll
        for (int i = 0; i < 4; ++i)
            *(f16x8*)&As[(arow_s + i * 32) * 64 + awx] = ra[i];
        #pragma unroll
        for (int i = 0; i < 8; ++i)
            *(f16x4*)&Bs[(brow_s + i * 16) * 64 + bwx] = cb[i];
        __syncthreads();
        if (kt + 1 < kts) {
            #pragma unroll
            for (int i = 0; i < 4; ++i) ra[i] = *(const f16x8*)(Ap + (size_t)i * 32 * lda + (kt + 1) * 64);
            #pragma unroll
            for (int i = 0; i < 8; ++i) rb[i] = *(const float4*)(Bp + (size_t)i * 16 * ldb + (kt + 1) * 64);
        }
        #pragma unroll
        for (int kk = 0; kk < 2; ++kk) {
            f16x8 af[4], bfr[4];
            #pragma unroll
            for (int m = 0; m < 4; ++m) af[m]  = *(const f16x8*)&As[(abase + m * 16 * 64 + kk * 32) ^ sxor];
            #pragma unroll
            for (int n = 0; n < 4; ++n) bfr[n] = *(const f16x8*)&Bs[(bbase + n * 16 * 64 + kk * 32) ^ sxor];
            #pragma unroll
            for (int m = 0; m < 4; ++m)
                #pragma unroll
                for (int n = 0; n < 4; ++n)
                    acc[m][n] = __builtin_amdgcn_mfma_f32_16x16x32_f16(af[m], bfr[n], acc[m][n], 0, 0, 0);
        }
    }

    const int ccol = nt * 128 + wc * 64 + (lane & 15);
    const int crow0 = mt * 128 + wr * 64 + ((lane >> 4) << 2);
    float bv[4];
    #pragma unroll
    for (int n = 0; n < 4; ++n) bv[n] = bias[ccol + n * 16];
    #pragma unroll
    for (int m = 0; m < 4; ++m) {
        #pragma unroll
        for (int rI = 0; rI < 4; ++rI) {
            const int row = crow0 + m * 16 + rI;
            if (row < Mvalid) {
                if (c16) {
                    _Float16* C = (_Float16*)Cv;
                    #pragma unroll
                    for (int n = 0; n < 4; ++n)
                        C[(size_t)row * ldc + ccol + n * 16] = (_Float16)(acc[m][n][rI] + bv[n]);
                } else {
                    float* C = (float*)Cv;
                    #pragma unroll
                    for (int n = 0; n < 4; ++n)
                        C[(size_t)row * ldc + ccol + n * 16] = acc[m][n][rI] + bv[n];
                }
            }
        }
    }
}

// ================= launch =================
extern "C" void kernel_launch(void* const* d_in, const int* in_sizes, int n_in,
                              void* d_out, int out_size, void* d_ws, size_t ws_size,
                              hipStream_t stream) {
    const int*   src     = (const int*)d_in[0];
    const int*   trg     = (const int*)d_in[1];
    const float* enc_emb = (const float*)d_in[2];
    const float* Wf_ih   = (const float*)d_in[3];
    const float* Wf_hh   = (const float*)d_in[4];
    const float* bf      = (const float*)d_in[5];
    const float* Wb_ih   = (const float*)d_in[6];
    const float* Wb_hh   = (const float*)d_in[7];
    const float* bb      = (const float*)d_in[8];
    const float* Wa      = (const float*)d_in[9];
    const float* ba      = (const float*)d_in[10];
    const float* vvec    = (const float*)d_in[11];
    const float* dec_emb = (const float*)d_in[12];
    const float* Wd_ih   = (const float*)d_in[13];
    const float* Wd_hh   = (const float*)d_in[14];
    const float* bd      = (const float*)d_in[15];
    const float* Wo      = (const float*)d_in[16];
    const float* bo      = (const float*)d_in[17];
    float* out = (float*)d_out;

    char* w = (char*)d_ws;
    _Float16* Wenc16     = (_Float16*)(w);               // 8,388,608 B
    _Float16* Wd16       = (_Float16*)(w + 8388608);     // 20,971,520 B
    _Float16* Wa16       = (_Float16*)(w + 29360128);    // 524,288 B
    _Float16* emb_src16  = (_Float16*)(w + 29884416);    // 8,388,608 B
    _Float16* enc_out16  = (_Float16*)(w + 38273024);    // 16,777,216 B
    _Float16* predA      = (_Float16*)(w + 55050240);    // 21,299,200 B (4160 x 2560)
    _Float16* h16_enc    = (_Float16*)(w + 76349440);    // 262,144 B
    float*    c_enc      = (float*)   (w + 76611584);    // 524,288 B
    float*    c_dec      = (float*)   (w + 77135872);    // 524,288 B
    float*    hatt       = (float*)   (w + 77660160);    // 65,536 B
    _Float16* enc_part16 = (_Float16*)(w + 77725696);    // 4,194,304 B
    int*      bar_ws     = (int*)     (w + 81920000);    // 2,621,440 B: 640 slots x 4KB
    const size_t need_bytes = 84541440;
    if (ws_size < need_bytes) return;

    init_convert<<<93888, 256, 0, stream>>>(
        src, trg, enc_emb, dec_emb, Wf_ih, Wf_hh, Wb_ih, Wb_hh, Wa, Wd_ih, Wd_hh,
        out, Wenc16, Wd16, Wa16, emb_src16, predA, c_enc, h16_enc, bar_ws);

    // ---- encoder (cooperative, 4 independent 64-block groups; fallback per-step) ----
    {
        const _Float16* a0 = Wenc16; const _Float16* a1 = emb_src16;
        _Float16* a2 = h16_enc; float* a3 = c_enc;
        const float* a4 = bf; const float* a5 = bb;
        _Float16* a6 = enc_out16; int* a7 = bar_ws;
        void* args[] = { &a0, &a1, &a2, &a3, &a4, &a5, &a6, &a7 };
        hipError_t e = hipLaunchCooperativeKernel((const void*)enc_coop, dim3(256), dim3(256), args, 0, stream);
        if (e != hipSuccess) {
            for (int s = 0; s < SLEN; ++s)
                enc_step_mfma<<<256, 64, 0, stream>>>(Wenc16, emb_src16, h16_enc, c_enc, bf, bb, enc_out16, s);
        }
    }

    // enc_part16 = enc_out16 @ Wa[:,1024:]^T + ba
    gemm_a16<<<128, 256, 0, stream>>>(enc_out16, 1024, Wa + 1024, 2048, ba,
                                      enc_part16, 256, 1024, 8192, 2, 1);

    // ---- decoder (cooperative, 64 attn(1d) + 192 gate(5d) blocks, Wd in LDS; fallback per-step) ----
    {
        const _Float16* a0 = Wd16; const _Float16* a1 = Wa16;
        const float* a2 = bd; const float* a3 = vvec;
        const int* a4 = src; const _Float16* a5 = enc_part16;
        const _Float16* a6 = enc_out16; const float* a7 = c_enc;
        _Float16* a8 = predA; int* a9 = bar_ws;
        void* args[] = { &a0, &a1, &a2, &a3, &a4, &a5, &a6, &a7, &a8, &a9 };
        hipError_t e = hipLaunchCooperativeKernel((const void*)dec_coop, dim3(256), dim3(256), args, 0, stream);
        if (e != hipSuccess) {
            dec_init<<<512, 256, 0, stream>>>(enc_out16, c_enc, predA, c_dec);
            for (int t = 0; t < TSTEPS; ++t) {
                hatt_mfma<<<16, 64, 0, stream>>>(predA, Wa16, hatt, t);
                attn_step<<<64, 256, 0, stream>>>(src, hatt, vvec, enc_part16, enc_out16, predA, t);
                dec_gates<<<256, 64, 0, stream>>>(Wd16, bd, c_dec, predA, t);
            }
        }
    }

    // out[64.. , :] = predA[64..] @ Wo^T + bo
    gemm_a16<<<8000, 256, 0, stream>>>(predA + (size_t)64 * 2560, 2560, Wo, 2560, bo,
                                       out + (size_t)64 * VOC, VOC, 2560, 4032, 250, 0);
}